// Round 3
// baseline (931.032 us; speedup 1.0000x reference)
//
#include <hip/hip_runtime.h>
#include <cstddef>

#define LOG2PI_F 1.8378770664093453f

typedef float f2 __attribute__((ext_vector_type(2)));

__device__ __forceinline__ float wave_sum(float v) {
#pragma unroll
    for (int o = 32; o >= 1; o >>= 1) v += __shfl_xor(v, o, 64);
    return v;
}
__device__ __forceinline__ float wave_max(float v) {
#pragma unroll
    for (int o = 32; o >= 1; o >>= 1) v = fmaxf(v, __shfl_xor(v, o, 64));
    return v;
}
__device__ __forceinline__ float wave_scan_incl(float v, int lane) {
#pragma unroll
    for (int o = 1; o < 64; o <<= 1) {
        float t = __shfl_up(v, o, 64);
        if (lane >= o) v += t;
    }
    return v;
}

// 16-element dot via packed f32 (v_pk_fma_f32): a,b as 8x float2.
__device__ __forceinline__ float dot16(const f2* __restrict__ a, const f2* __restrict__ b) {
    f2 dv = a[0] * b[0];
#pragma unroll
    for (int l = 1; l < 8; ++l) dv = __builtin_elementwise_fma(a[l], b[l], dv);
    return dv.x + dv.y;
}

// ---------------------------------------------------------------------------
// Per selected gene: softmax widths, bin locations, packed per-step table.
// Layout [gene][slot] (block-uniform in the gh-bucketed main kernel).
// slot SO[lev]+j: (uh[OH+j+1], 0.5*w[j], loc[j+1], 0);  slot 127: level-start uh.
// Also zeroes counts[g].
__global__ void k_prep_genes(const int* __restrict__ genes_oi,
                             const float* __restrict__ uh, const float* __restrict__ uw,
                             float4* __restrict__ pk, int* __restrict__ counts) {
    const int g = blockIdx.x;
    const int t = threadIdx.x;
    if (t == 0) counts[g] = 0;
    const int gs = genes_oi[g];
    const float* uhg = uh + (size_t)gs * 224;
    const float* uwg = uw + (size_t)gs * 221;
    float4* pkg = pk + (size_t)g * 224;

    const int NH[3] = {128, 64, 32};
    const int OH[3] = {0, 128, 192};
    const int OW[3] = {0, 127, 190};
    const int SO[3] = {0, 128, 191};
#pragma unroll
    for (int lev = 0; lev < 3; ++lev) {
        const int nw = NH[lev] - 1;
        float v0 = (t < nw)      ? uwg[OW[lev] + t]      : -INFINITY;
        float v1 = (t + 64 < nw) ? uwg[OW[lev] + t + 64] : -INFINITY;
        float mx = wave_max(fmaxf(v0, v1));
        float e0 = (t < nw)      ? __expf(v0 - mx) : 0.f;
        float e1 = (t + 64 < nw) ? __expf(v1 - mx) : 0.f;
        float inv = 1.0f / wave_sum(e0 + e1);
        float w0 = e0 * inv, w1 = e1 * inv;
        float i0 = wave_scan_incl(w0, t);
        float tot0 = __shfl(i0, 63, 64);
        float i1 = wave_scan_incl(w1, t) + tot0;
        if (t < nw) {
            float loc = (t == nw - 1) ? 1.0f : i0;
            pkg[SO[lev] + t] = make_float4(uhg[OH[lev] + t + 1], 0.5f * w0, loc, 0.f);
        }
        if (t + 64 < nw) {
            int j = t + 64;
            float loc = (j == nw - 1) ? 1.0f : i1;
            pkg[SO[lev] + j] = make_float4(uhg[OH[lev] + j + 1], 0.5f * w1, loc, 0.f);
        }
    }
    if (t == 0) pkg[127] = make_float4(uhg[0], uhg[128], uhg[192], 0.f);
}

// ---------------------------------------------------------------------------
// Transpose lw_oi to (g, c, l) row-major; fused prior ssq for lw row + rw row.
__global__ void k_prep_lwT(const int* __restrict__ genes_oi,
                           const float* __restrict__ lw, const float* __restrict__ rw,
                           float* __restrict__ lwT, float* __restrict__ pB) {
    const int g = blockIdx.x;
    const int tid = threadIdx.x;
    const int gs = genes_oi[g];
    const float* src = lw + (size_t)gs * 3584;
    float* dst = lwT + (size_t)g * 3584;
    float acc = 0.f;
    if (tid < 224) {
        float vv[16];
#pragma unroll
        for (int l = 0; l < 16; ++l) {
            float v = src[l * 224 + tid];
            vv[l] = v;
            acc = fmaf(v, v, acc);
        }
        float4* d4 = (float4*)(dst + (size_t)tid * 16);
#pragma unroll
        for (int q = 0; q < 4; ++q)
            d4[q] = make_float4(vv[4 * q + 0], vv[4 * q + 1], vv[4 * q + 2], vv[4 * q + 3]);
    }
    if (tid < 16) { float v = rw[(size_t)gs * 16 + tid]; acc = fmaf(v, v, acc); }
    __shared__ float sm[256];
    sm[tid] = acc;
    __syncthreads();
    for (int o = 128; o > 0; o >>= 1) { if (tid < o) sm[tid] += sm[tid + o]; __syncthreads(); }
    if (tid == 0) pB[g] = 0.5f * sm[0] + 0.5f * LOG2PI_F * (3584.0f + 16.0f);
}

// ---------------------------------------------------------------------------
// D[b*G_oi+g][j] = dot(lwT[g][j], cl[b]) for all b,g,j. One block per g;
// lwT row held in registers, clustering staged in LDS; coalesced row stores.
__launch_bounds__(256)
__global__ void k_mixd(const float* __restrict__ clustering,
                       const float* __restrict__ lwT,
                       float* __restrict__ D, int G_oi, int B) {
    const int g = blockIdx.x;
    const int j = threadIdx.x;
    __shared__ float cls[8192];               // B*16 = 512*16
    for (int i = threadIdx.x; i < B * 16; i += 256) cls[i] = clustering[i];
    __syncthreads();
    if (j >= 224) return;
    f2 lwr[8];
    const float4* src = (const float4*)(lwT + ((size_t)g * 224 + j) * 16);
#pragma unroll
    for (int q = 0; q < 4; ++q) {
        float4 v = src[q];
        lwr[2 * q + 0] = (f2){v.x, v.y};
        lwr[2 * q + 1] = (f2){v.z, v.w};
    }
    for (int b = 0; b < B; ++b) {
        const f2* cb = (const f2*)(cls + b * 16);
        D[((size_t)b * G_oi + g) * 224 + j] = dot16(lwr, cb);
    }
}

// ---------------------------------------------------------------------------
// Fused: histogram over gh = local_gene_ix  +  logrb = log(rho_bias).
__global__ void k_hist_logrb(const int* __restrict__ lgix, int* __restrict__ counts,
                             const float* __restrict__ rho_bias, float* __restrict__ logrb,
                             int N, int G_total) {
    int i = blockIdx.x * blockDim.x + threadIdx.x;
    if (i < G_total) logrb[i] = __logf(rho_bias[i]);
    if (i < N) atomicAdd(&counts[lgix[i]], 1);
}

__global__ void k_scan(const int* __restrict__ counts, int* __restrict__ offsets,
                       int* __restrict__ cursor, int G_oi) {
    __shared__ int sm[512];
    const int t = threadIdx.x;
    int v = (t < G_oi) ? counts[t] : 0;
    sm[t] = v;
    __syncthreads();
    for (int o = 1; o < 512; o <<= 1) {
        int add = (t >= o) ? sm[t - o] : 0;
        __syncthreads();
        sm[t] += add;
        __syncthreads();
    }
    if (t < G_oi) {
        offsets[t + 1] = sm[t];
        cursor[t] = sm[t] - v;
    }
    if (t == 0) offsets[0] = 0;
}

// Scatter, bucketed by gh: record = {x, lcx, lc2, 0}.
__global__ void k_scatter(const float* __restrict__ coord, const int* __restrict__ lgix,
                          const int* __restrict__ lcx, const int* __restrict__ lc2,
                          int* __restrict__ cursor, float4* __restrict__ xv, int N) {
    int i = blockIdx.x * blockDim.x + threadIdx.x;
    if (i >= N) return;
    int pos = atomicAdd(&cursor[lgix[i]], 1);
    xv[pos] = make_float4(coord[i], __int_as_float(lcx[i]), __int_as_float(lc2[i]), 0.f);
}

// ---------------------------------------------------------------------------
// Per-cell log-sum-exp; 2 cells per block (256 blocks -> all CUs busy).
__global__ void k_lse2(const float* __restrict__ clustering, const float* __restrict__ rw,
                       const float* __restrict__ logrb, float* __restrict__ lse,
                       int G_total, int B) {
    const int b0 = blockIdx.x * 2;
    const int tid = threadIdx.x;
    const int nc = min(2, B - b0);

    f2 cl[2][8];
#pragma unroll
    for (int c = 0; c < 2; ++c) {
        if (c < nc) {
            const float4* c4 = (const float4*)(clustering + (size_t)(b0 + c) * 16);
#pragma unroll
            for (int q = 0; q < 4; ++q) {
                float4 v = c4[q];
                cl[c][2 * q + 0] = (f2){v.x, v.y};
                cl[c][2 * q + 1] = (f2){v.z, v.w};
            }
        } else {
#pragma unroll
            for (int l = 0; l < 8; ++l) cl[c][l] = (f2){0.f, 0.f};
        }
    }

    float m[2], s[2];
#pragma unroll
    for (int c = 0; c < 2; ++c) { m[c] = -INFINITY; s[c] = 0.f; }

    for (int g = tid; g < G_total; g += 256) {
        const float4* r4 = (const float4*)(rw + (size_t)g * 16);
        f2 rv[8];
#pragma unroll
        for (int q = 0; q < 4; ++q) {
            float4 v = r4[q];
            rv[2 * q + 0] = (f2){v.x, v.y};
            rv[2 * q + 1] = (f2){v.z, v.w};
        }
        const float lb = logrb[g];
#pragma unroll
        for (int c = 0; c < 2; ++c) {
            float d = dot16(cl[c], rv);
            float logit = lb + d;
            float mn = fmaxf(m[c], logit);
            s[c] = s[c] * __expf(m[c] - mn) + __expf(logit - mn);
            m[c] = mn;
        }
    }

    __shared__ float ms[2][256], ss[2][256];
#pragma unroll
    for (int c = 0; c < 2; ++c) { ms[c][tid] = m[c]; ss[c][tid] = s[c]; }
    __syncthreads();
    for (int o = 128; o > 0; o >>= 1) {
        if (tid < o) {
#pragma unroll
            for (int c = 0; c < 2; ++c) {
                float m2 = ms[c][tid + o], s2 = ss[c][tid + o];
                float mn = fmaxf(ms[c][tid], m2);
                ss[c][tid] = ss[c][tid] * __expf(ms[c][tid] - mn) + s2 * __expf(m2 - mn);
                ms[c][tid] = mn;
            }
        }
        __syncthreads();
    }
    if (tid < 2 && tid < nc) lse[b0 + tid] = ms[tid][0] + __logf(ss[tid][0]);
}

// ---------------------------------------------------------------------------
// Main, bucketed by gh: pk table block-uniform in LDS (broadcast reads);
// per-cut D row read sequentially as float4 (coalesced per-lane lines).
__launch_bounds__(512, 4)
__global__ void k_main3(const float4* __restrict__ xv,
                        const int* __restrict__ offsets,
                        const float* __restrict__ clustering,
                        const float4* __restrict__ pk,   // [gene][224]
                        const float* __restrict__ D,     // [B*G_oi][224]
                        const float* __restrict__ rw,
                        const float* __restrict__ logrb,
                        const float* __restrict__ lse,
                        float* __restrict__ pA, int G_oi, int G_total) {
    const int g = blockIdx.x;
    const int tid = threadIdx.x;
    __shared__ float4 s_pk[224];
    __shared__ float wsm[8];
    if (tid < 224) s_pk[tid] = pk[(size_t)g * 224 + tid];
    __syncthreads();

    const int s = offsets[g], e = offsets[g + 1];
    const float logGt = __logf((float)G_total);
    const float4 uh0 = s_pk[127];
    float acc = 0.f;

    for (int base = s; base < e; base += 512) {
        const int i = base + tid;
        if (i < e) {
            float4 vv = xv[i];
            float x = vv.x;
            const int lcx = __float_as_int(vv.y);
            const int lc2 = __float_as_int(vv.z);
            const float* Drow = D + (size_t)lcx * 224;

            float lad = 0.f;
            const int NH[3] = {128, 64, 32};
            const int OH[3] = {0, 128, 192};
            const int SO[3] = {0, 128, 191};
#pragma unroll
            for (int lev = 0; lev < 3; ++lev) {
                const int nh = NH[lev];
                const float* dbase = Drow + OH[lev];
                const float uh0l = (lev == 0) ? uh0.x : ((lev == 1) ? uh0.y : uh0.z);
                const float4* spk = s_pk + SO[lev];

                float4 dq = *(const float4*)(dbase);
                float hp = __expf(uh0l + dq.x);
                float h_l = hp, h_r = hp, whb = 0.f, loc_l = 0.f, cdf = 0.f, area = 0.f;
                int in = 0;

                auto STEP = [&](int j, float dval, bool last) {
                    float4 pkv = spk[j];
                    float hn = __expf(pkv.x + dval);
                    float seg = (hp + hn) * pkv.y;
                    if (in == j) { h_r = hn; whb = pkv.y; }
                    bool adv = (x >= pkv.z) && !last;
                    if (adv) { cdf += seg; h_l = hn; loc_l = pkv.z; in = j + 1; }
                    area += seg;
                    hp = hn;
                };

                STEP(0, dq.y, false);
                STEP(1, dq.z, false);
                STEP(2, dq.w, false);
                const int nq = nh / 4;
                for (int q = 1; q < nq; ++q) {
                    dq = *(const float4*)(dbase + 4 * q);
                    const bool lastq = (q == nq - 1);
                    STEP(4 * q - 1, dq.x, false);
                    STEP(4 * q + 0, dq.y, false);
                    STEP(4 * q + 1, dq.z, false);
                    STEP(4 * q + 2, dq.w, lastq);
                }

                float inv_area = __builtin_amdgcn_rcpf(area);
                float alpha = (x - loc_l) * 0.5f * __builtin_amdgcn_rcpf(whb);
                float t2 = whb * alpha;
                x = (t2 * fmaf(h_r - h_l, alpha, 2.f * h_l) + cdf) * inv_area;
                lad += __logf(fmaf(h_r - h_l, alpha, h_l)) - __logf(area);
            }

            // lik_overall = logrb[gt] + cl[b2]·rw[gt] - lse[b2] + log(G_total)
            unsigned b2 = (unsigned)lc2 / (unsigned)G_total;
            unsigned gt = (unsigned)lc2 - b2 * (unsigned)G_total;
            f2 c2[8], r2[8];
            {
                const float4* c24 = (const float4*)(clustering + (size_t)b2 * 16);
                const float4* r4  = (const float4*)(rw + (size_t)gt * 16);
#pragma unroll
                for (int q = 0; q < 4; ++q) {
                    float4 a = c24[q], b = r4[q];
                    c2[2 * q + 0] = (f2){a.x, a.y}; c2[2 * q + 1] = (f2){a.z, a.w};
                    r2[2 * q + 0] = (f2){b.x, b.y}; r2[2 * q + 1] = (f2){b.z, b.w};
                }
            }
            float d2 = dot16(c2, r2);
            float lik = logrb[gt] + d2 - lse[b2] + logGt;
            acc -= (lad + lik);
        }
    }

    acc = wave_sum(acc);
    if ((tid & 63) == 0) wsm[tid >> 6] = acc;
    __syncthreads();
    if (tid == 0) {
        float t = 0.f;
#pragma unroll
        for (int w = 0; w < 8; ++w) t += wsm[w];
        pA[g] = t;
    }
}

// ---------------------------------------------------------------------------
__global__ void k_final(const float* __restrict__ pA, const float* __restrict__ pB,
                        float* __restrict__ out, int nA, int nB) {
    const int tid = threadIdx.x;
    float acc = 0.f;
    for (int i = tid; i < nA; i += blockDim.x) acc += pA[i];
    for (int i = tid; i < nB; i += blockDim.x) acc += pB[i];
    __shared__ float sm[256];
    sm[tid] = acc;
    __syncthreads();
    for (int o = 128; o > 0; o >>= 1) { if (tid < o) sm[tid] += sm[tid + o]; __syncthreads(); }
    if (tid == 0) out[0] = sm[0];
}

// ---------------------------------------------------------------------------
extern "C" void kernel_launch(void* const* d_in, const int* in_sizes, int n_in,
                              void* d_out, int out_size, void* d_ws, size_t ws_size,
                              hipStream_t stream) {
    const float* clustering        = (const float*)d_in[0];
    const float* coordinates       = (const float*)d_in[1];
    const int*   genes_oi          = (const int*)d_in[2];
    const int*   local_gene_ix     = (const int*)d_in[3];
    const int*   local_cellxgene_ix= (const int*)d_in[4];
    const int*   localcellxgene_ix = (const int*)d_in[5];
    const float* lw                = (const float*)d_in[6];
    const float* rw                = (const float*)d_in[7];
    const float* rho_bias          = (const float*)d_in[8];
    const float* uh                = (const float*)d_in[9];
    const float* uw                = (const float*)d_in[10];

    const int G_total = in_sizes[8];                  // 20000
    const int G_oi    = in_sizes[2];                  // 500
    const int N       = in_sizes[1];                  // 200000
    const int L       = in_sizes[7] / G_total;        // 16
    const int B       = in_sizes[0] / L;              // 512

    size_t off = 0;
    char* base = (char*)d_ws;
    auto alloc = [&](size_t nbytes) {
        char* p = base + off;
        off = (off + nbytes + 15) & ~(size_t)15;
        return (void*)p;
    };
    float*  pA      = (float*)alloc(sizeof(float) * (G_oi + 16));
    float*  pB      = (float*)alloc(sizeof(float) * (G_oi + 16));
    float*  lse     = (float*)alloc(sizeof(float) * (B + 16));
    float*  logrb   = (float*)alloc(sizeof(float) * G_total);
    float*  lwT     = (float*)alloc(sizeof(float) * (size_t)G_oi * 3584);
    float4* pk      = (float4*)alloc(sizeof(float4) * (size_t)G_oi * 224);
    int*    counts  = (int*)alloc(sizeof(int) * 512);
    int*    offsets = (int*)alloc(sizeof(int) * 512);
    int*    cursor  = (int*)alloc(sizeof(int) * 512);
    float4* xv      = (float4*)alloc(sizeof(float4) * (size_t)N);
    float*  D       = (float*)alloc(sizeof(float) * (size_t)B * G_oi * 224);
    (void)ws_size;

    const int TPB = 256;
    k_prep_genes<<<G_oi, 64, 0, stream>>>(genes_oi, uh, uw, pk, counts);
    k_prep_lwT<<<G_oi, 256, 0, stream>>>(genes_oi, lw, rw, lwT, pB);
    k_mixd<<<G_oi, 256, 0, stream>>>(clustering, lwT, D, G_oi, B);
    k_hist_logrb<<<(N + TPB - 1) / TPB, TPB, 0, stream>>>(local_gene_ix, counts,
                                                          rho_bias, logrb, N, G_total);
    k_scan<<<1, 512, 0, stream>>>(counts, offsets, cursor, G_oi);
    k_scatter<<<(N + TPB - 1) / TPB, TPB, 0, stream>>>(coordinates, local_gene_ix,
                                                       local_cellxgene_ix, localcellxgene_ix,
                                                       cursor, xv, N);
    k_lse2<<<(B + 1) / 2, 256, 0, stream>>>(clustering, rw, logrb, lse, G_total, B);
    k_main3<<<G_oi, 512, 0, stream>>>(xv, offsets, clustering, pk, D,
                                      rw, logrb, lse, pA, G_oi, G_total);
    k_final<<<1, 256, 0, stream>>>(pA, pB, (float*)d_out, G_oi, G_oi);
}

// Round 4
// 599.421 us; speedup vs baseline: 1.5532x; 1.5532x over previous
//
#include <hip/hip_runtime.h>
#include <cstddef>

#define LOG2PI_F 1.8378770664093453f

typedef float f2 __attribute__((ext_vector_type(2)));

__device__ __forceinline__ float wave_sum(float v) {
#pragma unroll
    for (int o = 32; o >= 1; o >>= 1) v += __shfl_xor(v, o, 64);
    return v;
}
__device__ __forceinline__ float wave_max(float v) {
#pragma unroll
    for (int o = 32; o >= 1; o >>= 1) v = fmaxf(v, __shfl_xor(v, o, 64));
    return v;
}
__device__ __forceinline__ float wave_scan_incl(float v, int lane) {
#pragma unroll
    for (int o = 1; o < 64; o <<= 1) {
        float t = __shfl_up(v, o, 64);
        if (lane >= o) v += t;
    }
    return v;
}

// 16-element dot via packed f32 (v_pk_fma_f32): a,b as 8x float2.
__device__ __forceinline__ float dot16(const f2* __restrict__ a, const f2* __restrict__ b) {
    f2 dv = a[0] * b[0];
#pragma unroll
    for (int l = 1; l < 8; ++l) dv = __builtin_elementwise_fma(a[l], b[l], dv);
    return dv.x + dv.y;
}

// ---------------------------------------------------------------------------
// Fused per-gene prep: lwT transpose + prior ssq (all 256 threads), then
// wave 0 builds the packed spline table (transposed pk[slot*G_oi+g]) and
// zeroes counts[g]. No barriers inside the wave-0 part.
__global__ void k_prep_fused(const int* __restrict__ genes_oi,
                             const float* __restrict__ lw, const float* __restrict__ rw,
                             const float* __restrict__ uh, const float* __restrict__ uw,
                             float* __restrict__ lwT, float* __restrict__ pB,
                             float4* __restrict__ pk, int* __restrict__ counts, int G_oi) {
    const int g = blockIdx.x;
    const int tid = threadIdx.x;
    const int gs = genes_oi[g];
    const float* src = lw + (size_t)gs * 3584;
    float* dst = lwT + (size_t)g * 3584;
    float acc = 0.f;
    if (tid < 224) {
        float vv[16];
#pragma unroll
        for (int l = 0; l < 16; ++l) {
            float v = src[l * 224 + tid];
            vv[l] = v;
            acc = fmaf(v, v, acc);
        }
        float4* d4 = (float4*)(dst + (size_t)tid * 16);
#pragma unroll
        for (int q = 0; q < 4; ++q)
            d4[q] = make_float4(vv[4 * q + 0], vv[4 * q + 1], vv[4 * q + 2], vv[4 * q + 3]);
    }
    if (tid < 16) { float v = rw[(size_t)gs * 16 + tid]; acc = fmaf(v, v, acc); }
    __shared__ float sm[256];
    sm[tid] = acc;
    __syncthreads();
    for (int o = 128; o > 0; o >>= 1) { if (tid < o) sm[tid] += sm[tid + o]; __syncthreads(); }
    if (tid == 0) {
        pB[g] = 0.5f * sm[0] + 0.5f * LOG2PI_F * (3584.0f + 16.0f);
        counts[g] = 0;
    }

    // ---- wave 0: spline table ----
    if (tid < 64) {
        const int t = tid;
        const float* uhg = uh + (size_t)gs * 224;
        const float* uwg = uw + (size_t)gs * 221;
        const int NH[3] = {128, 64, 32};
        const int OH[3] = {0, 128, 192};
        const int OW[3] = {0, 127, 190};
        const int SO[3] = {0, 128, 191};
#pragma unroll
        for (int lev = 0; lev < 3; ++lev) {
            const int nw = NH[lev] - 1;
            float v0 = (t < nw)      ? uwg[OW[lev] + t]      : -INFINITY;
            float v1 = (t + 64 < nw) ? uwg[OW[lev] + t + 64] : -INFINITY;
            float mx = wave_max(fmaxf(v0, v1));
            float e0 = (t < nw)      ? __expf(v0 - mx) : 0.f;
            float e1 = (t + 64 < nw) ? __expf(v1 - mx) : 0.f;
            float inv = 1.0f / wave_sum(e0 + e1);
            float w0 = e0 * inv, w1 = e1 * inv;
            float i0 = wave_scan_incl(w0, t);
            float tot0 = __shfl(i0, 63, 64);
            float i1 = wave_scan_incl(w1, t) + tot0;
            if (t < nw) {
                float loc = (t == nw - 1) ? 1.0f : i0;
                pk[(size_t)(SO[lev] + t) * G_oi + g] = make_float4(uhg[OH[lev] + t + 1], 0.5f * w0, loc, 0.f);
            }
            if (t + 64 < nw) {
                int j = t + 64;
                float loc = (j == nw - 1) ? 1.0f : i1;
                pk[(size_t)(SO[lev] + j) * G_oi + g] = make_float4(uhg[OH[lev] + j + 1], 0.5f * w1, loc, 0.f);
            }
        }
        if (t == 0) pk[(size_t)127 * G_oi + g] = make_float4(uhg[0], uhg[128], uhg[192], 0.f);
    }
}

// ---------------------------------------------------------------------------
// Fused: histogram over gm = lcx % G_oi  +  logrb = log(rho_bias).
__global__ void k_hist_logrb(const int* __restrict__ lcx, int* __restrict__ counts,
                             const float* __restrict__ rho_bias, float* __restrict__ logrb,
                             int N, int G_oi, int G_total) {
    int i = blockIdx.x * blockDim.x + threadIdx.x;
    if (i < G_total) logrb[i] = __logf(rho_bias[i]);
    if (i < N) atomicAdd(&counts[(unsigned)lcx[i] % (unsigned)G_oi], 1);
}

__global__ void k_scan(const int* __restrict__ counts, int* __restrict__ offsets,
                       int* __restrict__ cursor, int G_oi) {
    __shared__ int sm[512];
    const int t = threadIdx.x;
    int v = (t < G_oi) ? counts[t] : 0;
    sm[t] = v;
    __syncthreads();
    for (int o = 1; o < 512; o <<= 1) {
        int add = (t >= o) ? sm[t - o] : 0;
        __syncthreads();
        sm[t] += add;
        __syncthreads();
    }
    if (t < G_oi) {
        offsets[t + 1] = sm[t];
        cursor[t] = sm[t] - v;
    }
    if (t == 0) offsets[0] = 0;
}

// Scatter with packed per-cut record: {x, b1<<16|gh, lc2, 0}.
__global__ void k_scatter(const float* __restrict__ coord, const int* __restrict__ lgix,
                          const int* __restrict__ lcx, const int* __restrict__ lc2,
                          int* __restrict__ cursor, float4* __restrict__ xv, int N, int G_oi) {
    int i = blockIdx.x * blockDim.x + threadIdx.x;
    if (i >= N) return;
    unsigned v = (unsigned)lcx[i];
    unsigned g = v % (unsigned)G_oi;
    int pos = atomicAdd(&cursor[g], 1);
    int b1 = (int)(v / (unsigned)G_oi);
    xv[pos] = make_float4(coord[i], __int_as_float((b1 << 16) | lgix[i]),
                          __int_as_float(lc2[i]), 0.f);
}

// ---------------------------------------------------------------------------
// Per-cell log-sum-exp; 2 cells per block, gene-pair prefetch (g, g+256) for
// memory-level parallelism. Per-thread accumulation order identical to the
// stride-256 loop -> bit-identical lse.
__global__ void k_lse2(const float* __restrict__ clustering, const float* __restrict__ rw,
                       const float* __restrict__ logrb, float* __restrict__ lse,
                       int G_total, int B) {
    const int b0 = blockIdx.x * 2;
    const int tid = threadIdx.x;
    const int nc = min(2, B - b0);

    f2 cl[2][8];
#pragma unroll
    for (int c = 0; c < 2; ++c) {
        if (c < nc) {
            const float4* c4 = (const float4*)(clustering + (size_t)(b0 + c) * 16);
#pragma unroll
            for (int q = 0; q < 4; ++q) {
                float4 v = c4[q];
                cl[c][2 * q + 0] = (f2){v.x, v.y};
                cl[c][2 * q + 1] = (f2){v.z, v.w};
            }
        } else {
#pragma unroll
            for (int l = 0; l < 8; ++l) cl[c][l] = (f2){0.f, 0.f};
        }
    }

    float m[2], s[2];
#pragma unroll
    for (int c = 0; c < 2; ++c) { m[c] = -INFINITY; s[c] = 0.f; }

    for (int g = tid; g < G_total; g += 512) {
        const int g2 = g + 256;
        const bool has2 = g2 < G_total;
        const float4* r4 = (const float4*)(rw + (size_t)g * 16);
        const float4* r4b = (const float4*)(rw + (size_t)(has2 ? g2 : g) * 16);
        float4 ra[4], rb[4];
#pragma unroll
        for (int q = 0; q < 4; ++q) { ra[q] = r4[q]; rb[q] = r4b[q]; }
        const float lb  = logrb[g];
        const float lb2 = logrb[has2 ? g2 : g];

        f2 rv[8];
#pragma unroll
        for (int q = 0; q < 4; ++q) {
            rv[2 * q + 0] = (f2){ra[q].x, ra[q].y};
            rv[2 * q + 1] = (f2){ra[q].z, ra[q].w};
        }
#pragma unroll
        for (int c = 0; c < 2; ++c) {
            float d = dot16(cl[c], rv);
            float logit = lb + d;
            float mn = fmaxf(m[c], logit);
            s[c] = s[c] * __expf(m[c] - mn) + __expf(logit - mn);
            m[c] = mn;
        }
        if (has2) {
#pragma unroll
            for (int q = 0; q < 4; ++q) {
                rv[2 * q + 0] = (f2){rb[q].x, rb[q].y};
                rv[2 * q + 1] = (f2){rb[q].z, rb[q].w};
            }
#pragma unroll
            for (int c = 0; c < 2; ++c) {
                float d = dot16(cl[c], rv);
                float logit = lb2 + d;
                float mn = fmaxf(m[c], logit);
                s[c] = s[c] * __expf(m[c] - mn) + __expf(logit - mn);
                m[c] = mn;
            }
        }
    }

    __shared__ float ms[2][256], ss[2][256];
#pragma unroll
    for (int c = 0; c < 2; ++c) { ms[c][tid] = m[c]; ss[c][tid] = s[c]; }
    __syncthreads();
    for (int o = 128; o > 0; o >>= 1) {
        if (tid < o) {
#pragma unroll
            for (int c = 0; c < 2; ++c) {
                float m2 = ms[c][tid + o], s2 = ss[c][tid + o];
                float mn = fmaxf(ms[c][tid], m2);
                ss[c][tid] = ss[c][tid] * __expf(ms[c][tid] - mn) + s2 * __expf(m2 - mn);
                ms[c][tid] = mn;
            }
        }
        __syncthreads();
    }
    if (tid < 2 && tid < nc) lse[b0 + tid] = ms[tid][0] + __logf(ss[tid][0]);
}

// ---------------------------------------------------------------------------
// Main: one block per gene (gm bucket). Chunk counting-sort by gh (pk gather
// locality); spline walk software-pipelined 4 steps deep: 4 pkv gathers + 4
// dot16s issued before the dependent STEP chain.
__launch_bounds__(512, 4)
__global__ void k_main2(const float4* __restrict__ xv,
                        const int* __restrict__ offsets,
                        const float* __restrict__ clustering,
                        const float* __restrict__ lwT,    // [g][224][16]
                        const float4* __restrict__ pk,    // [slot][G_oi] transposed
                        const float* __restrict__ rw,
                        const float* __restrict__ logrb,
                        const float* __restrict__ lse,
                        float* __restrict__ pA, int G_oi, int G_total) {
    const int g = blockIdx.x;
    const int tid = threadIdx.x;
    const float* lwg = lwT + (size_t)g * 3584;
    const int s = offsets[g], e = offsets[g + 1];
    const float logGt = __logf((float)G_total);
    float acc = 0.f;

    __shared__ int    s_cnt[512];
    __shared__ int    s_cur[512];
    __shared__ float4 s_v[512];
    __shared__ float  wsm[8];

    for (int base = s; base < e; base += 512) {
        const int cnt = min(512, e - base);
        const bool valid = tid < cnt;
        float4 v0 = xv[valid ? base + tid : s];
        const int gh_0 = __float_as_int(v0.y) & 0xffff;

        // --- counting sort of this chunk by gh ---
        s_cnt[tid] = 0;
        __syncthreads();
        if (valid) atomicAdd(&s_cnt[gh_0], 1);
        __syncthreads();
        int v = s_cnt[tid];
        for (int o = 1; o < 512; o <<= 1) {
            int add = (tid >= o) ? s_cnt[tid - o] : 0;
            __syncthreads();
            s_cnt[tid] += add;
            __syncthreads();
        }
        s_cur[tid] = s_cnt[tid] - v;   // exclusive start
        __syncthreads();
        if (valid) {
            int pos = atomicAdd(&s_cur[gh_0], 1);
            s_v[pos] = v0;
        }
        __syncthreads();

        if (valid) {
            float4 vv = s_v[tid];
            float x = vv.x;
            const int meta = __float_as_int(vv.y);
            const int gh  = meta & 0xffff;
            const int b1  = meta >> 16;
            const int lc2 = __float_as_int(vv.z);

            f2 cl[8];
            {
                const float4* c4 = (const float4*)(clustering + (size_t)b1 * 16);
#pragma unroll
                for (int q = 0; q < 4; ++q) {
                    float4 t4 = c4[q];
                    cl[2 * q + 0] = (f2){t4.x, t4.y};
                    cl[2 * q + 1] = (f2){t4.z, t4.w};
                }
            }
            const float4 uh0 = pk[(size_t)127 * G_oi + gh];
            const float uh0v[3] = {uh0.x, uh0.y, uh0.z};

            float lad = 0.f;
            const int NH[3] = {128, 64, 32};
            const int OH[3] = {0, 128, 192};
            const int SO[3] = {0, 128, 191};
#pragma unroll
            for (int lev = 0; lev < 3; ++lev) {
                const int nw = NH[lev] - 1;            // 127 / 63 / 31, all ≡ 3 (mod 4)
                const float* rowbase = lwg + (size_t)OH[lev] * 16;
                float hp = __expf(uh0v[lev] + dot16((const f2*)rowbase, cl));
                float h_l = hp, h_r = hp, whb = 0.f, loc_l = 0.f, cdf = 0.f, area = 0.f;
                int in = 0;
                const float4* pks = pk + (size_t)SO[lev] * G_oi + gh;

                auto STEP = [&](int j, float4 pkv, float d) {
                    float hn = __expf(pkv.x + d);
                    float seg = (hp + hn) * pkv.y;
                    if (in == j) { h_r = hn; whb = pkv.y; }
                    bool adv = (x >= pkv.z) && (j < nw - 1);
                    if (adv) { cdf += seg; h_l = hn; loc_l = pkv.z; in = j + 1; }
                    area += seg;
                    hp = hn;
                };

                int j = 0;
                for (; j + 3 < nw; j += 4) {
                    float4 q0 = pks[0];
                    float4 q1 = pks[(size_t)G_oi];
                    float4 q2 = pks[(size_t)2 * G_oi];
                    float4 q3 = pks[(size_t)3 * G_oi];
                    pks += (size_t)4 * G_oi;
                    float d0 = dot16((const f2*)(rowbase + (size_t)(j + 1) * 16), cl);
                    float d1 = dot16((const f2*)(rowbase + (size_t)(j + 2) * 16), cl);
                    float d2 = dot16((const f2*)(rowbase + (size_t)(j + 3) * 16), cl);
                    float d3 = dot16((const f2*)(rowbase + (size_t)(j + 4) * 16), cl);
                    STEP(j + 0, q0, d0);
                    STEP(j + 1, q1, d1);
                    STEP(j + 2, q2, d2);
                    STEP(j + 3, q3, d3);
                }
                {   // tail: exactly 3 steps
                    float4 q0 = pks[0];
                    float4 q1 = pks[(size_t)G_oi];
                    float4 q2 = pks[(size_t)2 * G_oi];
                    float d0 = dot16((const f2*)(rowbase + (size_t)(j + 1) * 16), cl);
                    float d1 = dot16((const f2*)(rowbase + (size_t)(j + 2) * 16), cl);
                    float d2 = dot16((const f2*)(rowbase + (size_t)(j + 3) * 16), cl);
                    STEP(j + 0, q0, d0);
                    STEP(j + 1, q1, d1);
                    STEP(j + 2, q2, d2);
                }

                float inv_area = __builtin_amdgcn_rcpf(area);
                float alpha = (x - loc_l) * 0.5f * __builtin_amdgcn_rcpf(whb);
                float t2 = whb * alpha;
                x = (t2 * fmaf(h_r - h_l, alpha, 2.f * h_l) + cdf) * inv_area;
                lad += __logf(fmaf(h_r - h_l, alpha, h_l)) - __logf(area);
            }

            // lik_overall = logrb[gt] + cl[b2]·rw[gt] - lse[b2] + log(G_total)
            unsigned b2 = (unsigned)lc2 / (unsigned)G_total;
            unsigned gt = (unsigned)lc2 - b2 * (unsigned)G_total;
            f2 c2[8], r2[8];
            {
                const float4* c24 = (const float4*)(clustering + (size_t)b2 * 16);
                const float4* r4  = (const float4*)(rw + (size_t)gt * 16);
#pragma unroll
                for (int q = 0; q < 4; ++q) {
                    float4 a = c24[q], b = r4[q];
                    c2[2 * q + 0] = (f2){a.x, a.y}; c2[2 * q + 1] = (f2){a.z, a.w};
                    r2[2 * q + 0] = (f2){b.x, b.y}; r2[2 * q + 1] = (f2){b.z, b.w};
                }
            }
            float d2v = dot16(c2, r2);
            float lik = logrb[gt] + d2v - lse[b2] + logGt;
            acc -= (lad + lik);
        }
    }

    acc = wave_sum(acc);
    if ((tid & 63) == 0) wsm[tid >> 6] = acc;
    __syncthreads();
    if (tid == 0) {
        float t = 0.f;
#pragma unroll
        for (int w = 0; w < 8; ++w) t += wsm[w];
        pA[g] = t;
    }
}

// ---------------------------------------------------------------------------
__global__ void k_final(const float* __restrict__ pA, const float* __restrict__ pB,
                        float* __restrict__ out, int nA, int nB) {
    const int tid = threadIdx.x;
    float acc = 0.f;
    for (int i = tid; i < nA; i += blockDim.x) acc += pA[i];
    for (int i = tid; i < nB; i += blockDim.x) acc += pB[i];
    __shared__ float sm[256];
    sm[tid] = acc;
    __syncthreads();
    for (int o = 128; o > 0; o >>= 1) { if (tid < o) sm[tid] += sm[tid + o]; __syncthreads(); }
    if (tid == 0) out[0] = sm[0];
}

// ---------------------------------------------------------------------------
extern "C" void kernel_launch(void* const* d_in, const int* in_sizes, int n_in,
                              void* d_out, int out_size, void* d_ws, size_t ws_size,
                              hipStream_t stream) {
    const float* clustering        = (const float*)d_in[0];
    const float* coordinates       = (const float*)d_in[1];
    const int*   genes_oi          = (const int*)d_in[2];
    const int*   local_gene_ix     = (const int*)d_in[3];
    const int*   local_cellxgene_ix= (const int*)d_in[4];
    const int*   localcellxgene_ix = (const int*)d_in[5];
    const float* lw                = (const float*)d_in[6];
    const float* rw                = (const float*)d_in[7];
    const float* rho_bias          = (const float*)d_in[8];
    const float* uh                = (const float*)d_in[9];
    const float* uw                = (const float*)d_in[10];

    const int G_total = in_sizes[8];                  // 20000
    const int G_oi    = in_sizes[2];                  // 500
    const int N       = in_sizes[1];                  // 200000
    const int L       = in_sizes[7] / G_total;        // 16
    const int B       = in_sizes[0] / L;              // 512

    size_t off = 0;
    char* base = (char*)d_ws;
    auto alloc = [&](size_t nbytes) {
        char* p = base + off;
        off = (off + nbytes + 15) & ~(size_t)15;
        return (void*)p;
    };
    float*  pA      = (float*)alloc(sizeof(float) * (G_oi + 16));
    float*  pB      = (float*)alloc(sizeof(float) * (G_oi + 16));
    float*  lse     = (float*)alloc(sizeof(float) * (B + 16));
    float*  logrb   = (float*)alloc(sizeof(float) * G_total);
    float*  lwT     = (float*)alloc(sizeof(float) * (size_t)G_oi * 3584);
    float4* pk      = (float4*)alloc(sizeof(float4) * (size_t)G_oi * 224);
    int*    counts  = (int*)alloc(sizeof(int) * 512);
    int*    offsets = (int*)alloc(sizeof(int) * 512);
    int*    cursor  = (int*)alloc(sizeof(int) * 512);
    float4* xv      = (float4*)alloc(sizeof(float4) * (size_t)N);
    (void)ws_size;

    const int TPB = 256;
    k_prep_fused<<<G_oi, 256, 0, stream>>>(genes_oi, lw, rw, uh, uw, lwT, pB, pk, counts, G_oi);
    k_hist_logrb<<<(N + TPB - 1) / TPB, TPB, 0, stream>>>(local_cellxgene_ix, counts,
                                                          rho_bias, logrb, N, G_oi, G_total);
    k_scan<<<1, 512, 0, stream>>>(counts, offsets, cursor, G_oi);
    k_scatter<<<(N + TPB - 1) / TPB, TPB, 0, stream>>>(coordinates, local_gene_ix,
                                                       local_cellxgene_ix, localcellxgene_ix,
                                                       cursor, xv, N, G_oi);
    k_lse2<<<(B + 1) / 2, 256, 0, stream>>>(clustering, rw, logrb, lse, G_total, B);
    k_main2<<<G_oi, 512, 0, stream>>>(xv, offsets, clustering, lwT, pk,
                                      rw, logrb, lse, pA, G_oi, G_total);
    k_final<<<1, 256, 0, stream>>>(pA, pB, (float*)d_out, G_oi, G_oi);
}